// Round 6
// baseline (137.352 us; speedup 1.0000x reference)
//
#include <hip/hip_runtime.h>
#include <math.h>

#define NATOMS 21
#define DESC 210
#define DPAD 224          // padded descriptor count
#define P4 112            // DPAD/2 — float4-packed descriptor pairs
#define NTRAIN 4096
#define NM 128

#define CC 0.0f
#define STDC 1.0f
// q = sqrt(5)/sig
#define QS 0.22360679774997896f
// 5/(3*sig^2)
#define KE 0.016666666666666666f

#define R1 7              // bjq rows per pass1 chunk
#define NC1 16            // 112/7 chunks

// async global->LDS, 16B per lane, no VGPR round trip (guide §5 / T3)
__device__ __forceinline__ void gll16(const void* gptr, void* lptr) {
    __builtin_amdgcn_global_load_lds(
        (__attribute__((address_space(1))) void*)gptr,
        (__attribute__((address_space(3))) void*)lptr,
        16, 0, 0);
}

__device__ __forceinline__ void pair_ij(int p, int& i, int& j) {
    int ii = (int)((1.0f + sqrtf(1.0f + 8.0f * (float)p)) * 0.5f);
    while (ii * (ii - 1) / 2 > p) --ii;
    while ((ii + 1) * ii / 2 <= p) ++ii;
    i = ii;
    j = p - ii * (ii - 1) / 2;
}

// prep: blocks [0,448) transpose+pack xs/Jx into bjq and accumulate bsq/cj per t;
//       blocks [448,576) build per-molecule descriptors aT, asq.
__global__ __launch_bounds__(256, 2) void k_prep(const float* __restrict__ Rs,
                                                 const float* __restrict__ xs_train,
                                                 const float* __restrict__ Jx,
                                                 float4* __restrict__ bjq,
                                                 float* __restrict__ aT,
                                                 float* __restrict__ asq,
                                                 float* __restrict__ bsqA,
                                                 float* __restrict__ cjA) {
    __shared__ float smem[2 * 32 * 65 + 8];
    const int tid = threadIdx.x;
    const int bid = blockIdx.x;
    if (bid < 448) {
        float* ldsX = smem;
        float* ldsJ = smem + 32 * 65;
        const int bx = bid & 63;        // t tile
        const int by = bid >> 6;        // d tile (0..6)
        const int t0 = bx * 64;
        const int d0 = by * 32;
        #pragma unroll
        for (int k = 0; k < 8; ++k) {
            const int idx = tid + k * 256;        // 64t x 32d
            const int tt = idx >> 5;
            const int dd = idx & 31;
            const int d = d0 + dd;
            float xv = 0.0f, jv = 0.0f;
            if (d < DESC) {
                xv = QS * xs_train[(t0 + tt) * DESC + d];
                jv = Jx[(t0 + tt) * DESC + d];
            }
            ldsX[dd * 65 + tt] = xv;
            ldsJ[dd * 65 + tt] = jv;
        }
        __syncthreads();
        #pragma unroll
        for (int k = 0; k < 4; ++k) {
            const int idx = tid + k * 256;        // 16p x 64t
            const int pp = idx >> 6;
            const int tt = idx & 63;
            float4 v;
            v.x = ldsX[(2 * pp) * 65 + tt];
            v.y = ldsJ[(2 * pp) * 65 + tt];
            v.z = ldsX[(2 * pp + 1) * 65 + tt];
            v.w = ldsJ[(2 * pp + 1) * 65 + tt];
            bjq[(by * 16 + pp) * NTRAIN + t0 + tt] = v;
        }
        // per-t partials of sum_d b^2 and sum_d b*j over this 32-d tile
        if (tid < 64) {
            float sb = 0.0f, sc = 0.0f;
            #pragma unroll
            for (int dd = 0; dd < 32; ++dd) {
                const float b = ldsX[dd * 65 + tid];
                const float jj = ldsJ[dd * 65 + tid];
                sb = fmaf(b, b, sb);
                sc = fmaf(b, jj, sc);
            }
            atomicAdd(&bsqA[t0 + tid], sb);
            atomicAdd(&cjA[t0 + tid], sc);
        }
    } else {
        const int m = bid - 448;
        float* R = smem;
        float* red = smem + 64;
        if (tid < NATOMS * 3) R[tid] = Rs[m * NATOMS * 3 + tid];
        __syncthreads();
        float a2 = 0.0f;
        if (tid < DPAD) {
            float a = 0.0f;
            if (tid < DESC) {
                int i, j;
                pair_ij(tid, i, j);
                const float dx = R[i * 3 + 0] - R[j * 3 + 0];
                const float dy = R[i * 3 + 1] - R[j * 3 + 1];
                const float dz = R[i * 3 + 2] - R[j * 3 + 2];
                a = QS / sqrtf(dx * dx + dy * dy + dz * dz);
            }
            aT[tid * NM + m] = a;
            a2 = a * a;
        }
        #pragma unroll
        for (int off = 32; off > 0; off >>= 1) a2 += __shfl_down(a2, off, 64);
        if ((tid & 63) == 0) red[tid >> 6] = a2;
        __syncthreads();
        if (tid == 0) asq[m] = red[0] + red[1] + red[2] + red[3];
    }
}

// pass 1: P/Q via global_load_lds double-buffered K loop (T3 2-phase recipe).
// Block 256 t-lanes x 8 m; 16 chunks of 7 bjq rows.
__global__ __launch_bounds__(256, 2) void k_pass1(const float4* __restrict__ bjq,
                                                  const float* __restrict__ aT,
                                                  const float* __restrict__ asq,
                                                  const float* __restrict__ bsqA,
                                                  const float* __restrict__ cjA,
                                                  float2* __restrict__ w12,
                                                  float* __restrict__ EsAcc,
                                                  float* __restrict__ S1) {
    const int tid = threadIdx.x;
    const int t0 = blockIdx.x * 256;
    const int m0 = blockIdx.y * 8;
    const int t = t0 + tid;
    const int wbase = tid & ~63;   // wave-uniform LDS segment base

    __shared__ __align__(16) float aS[P4][16];           // 7 KB: [p]{d0:m0..7, d1:m0..7}
    __shared__ __align__(16) float4 bjS[2][R1 * 256];    // 2 x 28 KB

    #pragma unroll
    for (int k = 0; k < 7; ++k) {
        const int idx = tid + k * 256;     // 112*16 = 1792
        const int p = idx >> 4;
        const int c = idx & 15;
        aS[p][c] = aT[(2 * p + (c >> 3)) * NM + m0 + (c & 7)];
    }
    // stage chunk 0 (async; drained by the barrier)
    #pragma unroll
    for (int k = 0; k < R1; ++k)
        gll16(&bjq[k * NTRAIN + t], &bjS[0][k * 256 + wbase]);
    __syncthreads();

    float P[8] = {0.f, 0.f, 0.f, 0.f, 0.f, 0.f, 0.f, 0.f};
    float Q[8] = {0.f, 0.f, 0.f, 0.f, 0.f, 0.f, 0.f, 0.f};

    for (int c = 0; c < NC1; ++c) {
        const int cb = c & 1;
        // issue next chunk's loads BEFORE computing current (they fly during compute)
        if (c + 1 < NC1) {
            #pragma unroll
            for (int k = 0; k < R1; ++k)
                gll16(&bjq[((c + 1) * R1 + k) * NTRAIN + t], &bjS[1 - cb][k * 256 + wbase]);
        }
        #pragma unroll
        for (int u = 0; u < R1; ++u) {
            const int p = c * R1 + u;
            const float4 bj = bjS[cb][u * 256 + tid];
            const float4 aA = *reinterpret_cast<const float4*>(&aS[p][0]);
            const float4 aB = *reinterpret_cast<const float4*>(&aS[p][4]);
            const float4 aC = *reinterpret_cast<const float4*>(&aS[p][8]);
            const float4 aD = *reinterpret_cast<const float4*>(&aS[p][12]);
            P[0] = fmaf(aA.x, bj.x, P[0]); P[1] = fmaf(aA.y, bj.x, P[1]);
            P[2] = fmaf(aA.z, bj.x, P[2]); P[3] = fmaf(aA.w, bj.x, P[3]);
            P[4] = fmaf(aB.x, bj.x, P[4]); P[5] = fmaf(aB.y, bj.x, P[5]);
            P[6] = fmaf(aB.z, bj.x, P[6]); P[7] = fmaf(aB.w, bj.x, P[7]);
            Q[0] = fmaf(aA.x, bj.y, Q[0]); Q[1] = fmaf(aA.y, bj.y, Q[1]);
            Q[2] = fmaf(aA.z, bj.y, Q[2]); Q[3] = fmaf(aA.w, bj.y, Q[3]);
            Q[4] = fmaf(aB.x, bj.y, Q[4]); Q[5] = fmaf(aB.y, bj.y, Q[5]);
            Q[6] = fmaf(aB.z, bj.y, Q[6]); Q[7] = fmaf(aB.w, bj.y, Q[7]);
            P[0] = fmaf(aC.x, bj.z, P[0]); P[1] = fmaf(aC.y, bj.z, P[1]);
            P[2] = fmaf(aC.z, bj.z, P[2]); P[3] = fmaf(aC.w, bj.z, P[3]);
            P[4] = fmaf(aD.x, bj.z, P[4]); P[5] = fmaf(aD.y, bj.z, P[5]);
            P[6] = fmaf(aD.z, bj.z, P[6]); P[7] = fmaf(aD.w, bj.z, P[7]);
            Q[0] = fmaf(aC.x, bj.w, Q[0]); Q[1] = fmaf(aC.y, bj.w, Q[1]);
            Q[2] = fmaf(aC.z, bj.w, Q[2]); Q[3] = fmaf(aC.w, bj.w, Q[3]);
            Q[4] = fmaf(aD.x, bj.w, Q[4]); Q[5] = fmaf(aD.y, bj.w, Q[5]);
            Q[6] = fmaf(aD.z, bj.w, Q[6]); Q[7] = fmaf(aD.w, bj.w, Q[7]);
        }
        // drains next chunk's loads + fences buffer reuse
        __syncthreads();
    }

    const float bsqv = bsqA[t];
    const float cjv = cjA[t];
    float esv[8], s1v[8];
    #pragma unroll
    for (int mi = 0; mi < 8; ++mi) {
        float dist2 = asq[m0 + mi] + bsqv - 2.0f * P[mi];
        dist2 = fmaxf(dist2, 0.0f);
        const float x = sqrtf(dist2);
        const float e = KE * expf(-x);
        const float dotv = Q[mi] - cjv;
        const float w1v = e * dotv;
        const float w2v = e * (1.0f + x);
        w12[(m0 + mi) * NTRAIN + t] = make_float2(w1v, w2v);
        esv[mi] = w2v * dotv;
        s1v[mi] = w1v;
    }
    #pragma unroll
    for (int off = 32; off > 0; off >>= 1) {
        #pragma unroll
        for (int mi = 0; mi < 8; ++mi) {
            esv[mi] += __shfl_down(esv[mi], off, 64);
            s1v[mi] += __shfl_down(s1v[mi], off, 64);
        }
    }
    if ((tid & 63) == 0) {
        #pragma unroll
        for (int mi = 0; mi < 8; ++mi) {
            atomicAdd(&EsAcc[m0 + mi], esv[mi]);
            atomicAdd(&S1[m0 + mi], s1v[mi]);
        }
    }
}

// pass 2: F1[m,d] += sum_t w1[m,t]*q*xs[t,d]; F2[m,d] += sum_t w2[m,t]*Jx[t,d].
// Block 128 threads; thread = d-pair (2d, 2d+1), 8 m register tile, T=32 t-chunk.
// w-tile staged once via global_load_lds; xs/Jx per-lane coalesced float2.
__global__ __launch_bounds__(128, 4) void k_pass2(const float* __restrict__ xs_train,
                                                  const float* __restrict__ Jx,
                                                  const float2* __restrict__ w12,
                                                  float* __restrict__ F1acc,
                                                  float* __restrict__ F2acc) {
    const int tid = threadIdx.x;
    const int t0 = blockIdx.x * 32;
    const int m0 = blockIdx.y * 8;
    const int wbase = tid & ~63;

    __shared__ __align__(16) float2 wL[8][32];   // 2 KB: [mi][tt]

    // stage w-tile: float4 idx = tid covers (mi = tid>>4, tt = 2*(tid&15))
    gll16(&w12[(m0 + (tid >> 4)) * NTRAIN + t0 + 2 * (tid & 15)],
          &reinterpret_cast<float4*>(wL)[wbase]);

    const bool act = tid < 105;                  // 105 d-pairs cover 210 d
    const int dp = act ? tid : 104;

    float G1a[8] = {0.f, 0.f, 0.f, 0.f, 0.f, 0.f, 0.f, 0.f};
    float G1b[8] = {0.f, 0.f, 0.f, 0.f, 0.f, 0.f, 0.f, 0.f};
    float G2a[8] = {0.f, 0.f, 0.f, 0.f, 0.f, 0.f, 0.f, 0.f};
    float G2b[8] = {0.f, 0.f, 0.f, 0.f, 0.f, 0.f, 0.f, 0.f};

    __syncthreads();

    #pragma unroll 4
    for (int tt = 0; tt < 32; ++tt) {
        const int t = t0 + tt;
        const float2 xv = *reinterpret_cast<const float2*>(&xs_train[t * DESC + 2 * dp]);
        const float2 jv = *reinterpret_cast<const float2*>(&Jx[t * DESC + 2 * dp]);
        #pragma unroll
        for (int mi = 0; mi < 8; ++mi) {
            const float2 w = wL[mi][tt];
            G1a[mi] = fmaf(w.x, xv.x, G1a[mi]);
            G1b[mi] = fmaf(w.x, xv.y, G1b[mi]);
            G2a[mi] = fmaf(w.y, jv.x, G2a[mi]);
            G2b[mi] = fmaf(w.y, jv.y, G2b[mi]);
        }
    }

    if (act) {
        #pragma unroll
        for (int mi = 0; mi < 8; ++mi) {
            atomicAdd(&F1acc[(m0 + mi) * DESC + 2 * dp], QS * G1a[mi]);
            atomicAdd(&F1acc[(m0 + mi) * DESC + 2 * dp + 1], QS * G1b[mi]);
            atomicAdd(&F2acc[(m0 + mi) * DESC + 2 * dp], G2a[mi]);
            atomicAdd(&F2acc[(m0 + mi) * DESC + 2 * dp + 1], G2b[mi]);
        }
    }
}

// final assembly — coef, force scatter, Es
__global__ __launch_bounds__(256) void k_final(const float* __restrict__ Rs,
                                               const float* __restrict__ aT,
                                               const float* __restrict__ S1,
                                               const float* __restrict__ EsAcc,
                                               const float* __restrict__ F1acc,
                                               const float* __restrict__ F2acc,
                                               float* __restrict__ out) {
    const int m = blockIdx.x;
    __shared__ float R[NATOMS * 3];
    __shared__ float FsL[NATOMS * 3];
    const int tid = threadIdx.x;
    if (tid < NATOMS * 3) {
        R[tid] = Rs[m * NATOMS * 3 + tid];
        FsL[tid] = 0.0f;
    }
    __syncthreads();
    if (tid < DESC) {
        int i, j;
        pair_ij(tid, i, j);
        const float dx = R[i * 3 + 0] - R[j * 3 + 0];
        const float dy = R[i * 3 + 1] - R[j * 3 + 1];
        const float dz = R[i * 3 + 2] - R[j * 3 + 2];
        const float r2 = dx * dx + dy * dy + dz * dz;
        const float rinv = 1.0f / sqrtf(r2);
        const float a = aT[tid * NM + m];  // q/r
        const float F1 = a * S1[m] - F1acc[m * DESC + tid];
        const float Fx = (F1 - F2acc[m * DESC + tid]) * STDC;
        const float coef = Fx * (rinv * rinv * rinv);
        atomicAdd(&FsL[j * 3 + 0], coef * dx);
        atomicAdd(&FsL[j * 3 + 1], coef * dy);
        atomicAdd(&FsL[j * 3 + 2], coef * dz);
        atomicAdd(&FsL[i * 3 + 0], -coef * dx);
        atomicAdd(&FsL[i * 3 + 1], -coef * dy);
        atomicAdd(&FsL[i * 3 + 2], -coef * dz);
    }
    __syncthreads();
    if (tid < NATOMS * 3) out[NM + m * NATOMS * 3 + tid] = FsL[tid];
    if (tid == 0) out[m] = CC + (EsAcc[m] / QS) * STDC;
}

extern "C" void kernel_launch(void* const* d_in, const int* in_sizes, int n_in,
                              void* d_out, int out_size, void* d_ws, size_t ws_size,
                              hipStream_t stream) {
    const float* Rs = (const float*)d_in[0];
    const float* xs_train = (const float*)d_in[1];
    const float* Jx = (const float*)d_in[2];
    float* out = (float*)d_out;
    float* ws = (float*)d_ws;

    // zeroed prefix
    float* F1acc = ws;                         // 26880
    float* F2acc = ws + 26880;                 // 26880
    float* EsAcc = ws + 53760;                 // 128
    float* S1 = ws + 53888;                    // 128
    float* bsqA = ws + 54016;                  // 4096
    float* cjA = ws + 58112;                   // 4096  -> zero block ends at 62208
    // non-zeroed
    float* aT = ws + 62208;                    // 224*128 = 28672
    float* asq = ws + 90880;                   // 128
    float4* bjq = (float4*)(ws + 91008);       // 112*4096 float4 (16B aligned)
    float2* w12 = (float2*)(ws + 1926016);     // 128*4096 float2 (16B aligned)
    // end 2974592 floats (~11.9 MB)

    hipMemsetAsync(ws, 0, (size_t)62208 * sizeof(float), stream);

    k_prep<<<576, 256, 0, stream>>>(Rs, xs_train, Jx, bjq, aT, asq, bsqA, cjA);
    k_pass1<<<dim3(NTRAIN / 256, NM / 8), 256, 0, stream>>>(bjq, aT, asq, bsqA, cjA,
                                                            w12, EsAcc, S1);
    k_pass2<<<dim3(NTRAIN / 32, NM / 8), 128, 0, stream>>>(xs_train, Jx, w12,
                                                           F1acc, F2acc);
    k_final<<<NM, 256, 0, stream>>>(Rs, aT, S1, EsAcc, F1acc, F2acc, out);
}

// Round 7
// 93.869 us; speedup vs baseline: 1.4632x; 1.4632x over previous
//
#include <hip/hip_runtime.h>
#include <math.h>

#define NATOMS 21
#define DESC 210
#define DPAD 224          // padded descriptor count
#define P4 112            // DPAD/2 — float4-packed descriptor pairs
#define NTRAIN 4096
#define NM 128

#define CC 0.0f
#define STDC 1.0f
// q = sqrt(5)/sig
#define QS 0.22360679774997896f
// 5/(3*sig^2)
#define KE 0.016666666666666666f

#define R1 7              // bjq rows per pass1 chunk
#define NC1 16            // 112/7 chunks

// async global->LDS, 16B per lane, no VGPR round trip (guide §5 / T3)
__device__ __forceinline__ void gll16(const void* gptr, void* lptr) {
    __builtin_amdgcn_global_load_lds(
        (__attribute__((address_space(1))) void*)gptr,
        (__attribute__((address_space(3))) void*)lptr,
        16, 0, 0);
}

__device__ __forceinline__ void pair_ij(int p, int& i, int& j) {
    int ii = (int)((1.0f + sqrtf(1.0f + 8.0f * (float)p)) * 0.5f);
    while (ii * (ii - 1) / 2 > p) --ii;
    while ((ii + 1) * ii / 2 <= p) ++ii;
    i = ii;
    j = p - ii * (ii - 1) / 2;
}

// prep: blocks [0,448) transpose+pack xs/Jx into bjq (pass1) and xj2 (pass2),
//       accumulate bsq/cj per t; blocks [448,576) build aT, asq.
__global__ __launch_bounds__(256, 2) void k_prep(const float* __restrict__ Rs,
                                                 const float* __restrict__ xs_train,
                                                 const float* __restrict__ Jx,
                                                 float4* __restrict__ bjq,
                                                 float2* __restrict__ xj2,
                                                 float* __restrict__ aT,
                                                 float* __restrict__ asq,
                                                 float* __restrict__ bsqA,
                                                 float* __restrict__ cjA) {
    __shared__ float smem[2 * 32 * 65 + 8];
    const int tid = threadIdx.x;
    const int bid = blockIdx.x;
    if (bid < 448) {
        float* ldsX = smem;
        float* ldsJ = smem + 32 * 65;
        const int bx = bid & 63;        // t tile
        const int by = bid >> 6;        // d tile (0..6)
        const int t0 = bx * 64;
        const int d0 = by * 32;
        #pragma unroll
        for (int k = 0; k < 8; ++k) {
            const int idx = tid + k * 256;        // 64t x 32d
            const int tt = idx >> 5;
            const int dd = idx & 31;
            const int d = d0 + dd;
            float xv = 0.0f, jv = 0.0f;
            if (d < DESC) {
                xv = QS * xs_train[(t0 + tt) * DESC + d];
                jv = Jx[(t0 + tt) * DESC + d];
            }
            ldsX[dd * 65 + tt] = xv;
            ldsJ[dd * 65 + tt] = jv;
        }
        __syncthreads();
        #pragma unroll
        for (int k = 0; k < 4; ++k) {
            const int idx = tid + k * 256;        // 16p x 64t
            const int pp = idx >> 6;
            const int tt = idx & 63;
            float4 v;
            v.x = ldsX[(2 * pp) * 65 + tt];
            v.y = ldsJ[(2 * pp) * 65 + tt];
            v.z = ldsX[(2 * pp + 1) * 65 + tt];
            v.w = ldsJ[(2 * pp + 1) * 65 + tt];
            bjq[(by * 16 + pp) * NTRAIN + t0 + tt] = v;
        }
        // pass2 layout: xj2[t][256] = {q*xs, Jx}
        #pragma unroll
        for (int k = 0; k < 8; ++k) {
            const int idx = tid + k * 256;        // 64t x 32d
            const int tt = idx >> 5;
            const int dd = idx & 31;
            xj2[(t0 + tt) * 256 + d0 + dd] =
                make_float2(ldsX[dd * 65 + tt], ldsJ[dd * 65 + tt]);
        }
        // per-t partials of sum_d b^2 and sum_d b*j over this 32-d tile
        if (tid < 64) {
            float sb = 0.0f, sc = 0.0f;
            #pragma unroll
            for (int dd = 0; dd < 32; ++dd) {
                const float b = ldsX[dd * 65 + tid];
                const float jj = ldsJ[dd * 65 + tid];
                sb = fmaf(b, b, sb);
                sc = fmaf(b, jj, sc);
            }
            atomicAdd(&bsqA[t0 + tid], sb);
            atomicAdd(&cjA[t0 + tid], sc);
        }
    } else {
        const int m = bid - 448;
        float* R = smem;
        float* red = smem + 64;
        if (tid < NATOMS * 3) R[tid] = Rs[m * NATOMS * 3 + tid];
        __syncthreads();
        float a2 = 0.0f;
        if (tid < DPAD) {
            float a = 0.0f;
            if (tid < DESC) {
                int i, j;
                pair_ij(tid, i, j);
                const float dx = R[i * 3 + 0] - R[j * 3 + 0];
                const float dy = R[i * 3 + 1] - R[j * 3 + 1];
                const float dz = R[i * 3 + 2] - R[j * 3 + 2];
                a = QS / sqrtf(dx * dx + dy * dy + dz * dz);
            }
            aT[tid * NM + m] = a;
            a2 = a * a;
        }
        #pragma unroll
        for (int off = 32; off > 0; off >>= 1) a2 += __shfl_down(a2, off, 64);
        if ((tid & 63) == 0) red[tid >> 6] = a2;
        __syncthreads();
        if (tid == 0) asq[m] = red[0] + red[1] + red[2] + red[3];
    }
}

// pass 1: P/Q via global_load_lds double-buffered K loop (T3 2-phase recipe).
__global__ __launch_bounds__(256, 2) void k_pass1(const float4* __restrict__ bjq,
                                                  const float* __restrict__ aT,
                                                  const float* __restrict__ asq,
                                                  const float* __restrict__ bsqA,
                                                  const float* __restrict__ cjA,
                                                  float2* __restrict__ w12,
                                                  float* __restrict__ EsAcc,
                                                  float* __restrict__ S1) {
    const int tid = threadIdx.x;
    const int t0 = blockIdx.x * 256;
    const int m0 = blockIdx.y * 8;
    const int t = t0 + tid;
    const int wbase = tid & ~63;   // wave-uniform LDS segment base

    __shared__ __align__(16) float aS[P4][16];           // 7 KB: [p]{d0:m0..7, d1:m0..7}
    __shared__ __align__(16) float4 bjS[2][R1 * 256];    // 2 x 28 KB

    #pragma unroll
    for (int k = 0; k < 7; ++k) {
        const int idx = tid + k * 256;     // 112*16 = 1792
        const int p = idx >> 4;
        const int c = idx & 15;
        aS[p][c] = aT[(2 * p + (c >> 3)) * NM + m0 + (c & 7)];
    }
    // stage chunk 0 (async; drained by the barrier)
    #pragma unroll
    for (int k = 0; k < R1; ++k)
        gll16(&bjq[k * NTRAIN + t], &bjS[0][k * 256 + wbase]);
    __syncthreads();

    float P[8] = {0.f, 0.f, 0.f, 0.f, 0.f, 0.f, 0.f, 0.f};
    float Q[8] = {0.f, 0.f, 0.f, 0.f, 0.f, 0.f, 0.f, 0.f};

    for (int c = 0; c < NC1; ++c) {
        const int cb = c & 1;
        // issue next chunk's loads BEFORE computing current (they fly during compute)
        if (c + 1 < NC1) {
            #pragma unroll
            for (int k = 0; k < R1; ++k)
                gll16(&bjq[((c + 1) * R1 + k) * NTRAIN + t], &bjS[1 - cb][k * 256 + wbase]);
        }
        #pragma unroll
        for (int u = 0; u < R1; ++u) {
            const int p = c * R1 + u;
            const float4 bj = bjS[cb][u * 256 + tid];
            const float4 aA = *reinterpret_cast<const float4*>(&aS[p][0]);
            const float4 aB = *reinterpret_cast<const float4*>(&aS[p][4]);
            const float4 aC = *reinterpret_cast<const float4*>(&aS[p][8]);
            const float4 aD = *reinterpret_cast<const float4*>(&aS[p][12]);
            P[0] = fmaf(aA.x, bj.x, P[0]); P[1] = fmaf(aA.y, bj.x, P[1]);
            P[2] = fmaf(aA.z, bj.x, P[2]); P[3] = fmaf(aA.w, bj.x, P[3]);
            P[4] = fmaf(aB.x, bj.x, P[4]); P[5] = fmaf(aB.y, bj.x, P[5]);
            P[6] = fmaf(aB.z, bj.x, P[6]); P[7] = fmaf(aB.w, bj.x, P[7]);
            Q[0] = fmaf(aA.x, bj.y, Q[0]); Q[1] = fmaf(aA.y, bj.y, Q[1]);
            Q[2] = fmaf(aA.z, bj.y, Q[2]); Q[3] = fmaf(aA.w, bj.y, Q[3]);
            Q[4] = fmaf(aB.x, bj.y, Q[4]); Q[5] = fmaf(aB.y, bj.y, Q[5]);
            Q[6] = fmaf(aB.z, bj.y, Q[6]); Q[7] = fmaf(aB.w, bj.y, Q[7]);
            P[0] = fmaf(aC.x, bj.z, P[0]); P[1] = fmaf(aC.y, bj.z, P[1]);
            P[2] = fmaf(aC.z, bj.z, P[2]); P[3] = fmaf(aC.w, bj.z, P[3]);
            P[4] = fmaf(aD.x, bj.z, P[4]); P[5] = fmaf(aD.y, bj.z, P[5]);
            P[6] = fmaf(aD.z, bj.z, P[6]); P[7] = fmaf(aD.w, bj.z, P[7]);
            Q[0] = fmaf(aC.x, bj.w, Q[0]); Q[1] = fmaf(aC.y, bj.w, Q[1]);
            Q[2] = fmaf(aC.z, bj.w, Q[2]); Q[3] = fmaf(aC.w, bj.w, Q[3]);
            Q[4] = fmaf(aD.x, bj.w, Q[4]); Q[5] = fmaf(aD.y, bj.w, Q[5]);
            Q[6] = fmaf(aD.z, bj.w, Q[6]); Q[7] = fmaf(aD.w, bj.w, Q[7]);
        }
        // drains next chunk's loads + fences buffer reuse
        __syncthreads();
    }

    const float bsqv = bsqA[t];
    const float cjv = cjA[t];
    float esv[8], s1v[8];
    #pragma unroll
    for (int mi = 0; mi < 8; ++mi) {
        float dist2 = asq[m0 + mi] + bsqv - 2.0f * P[mi];
        dist2 = fmaxf(dist2, 0.0f);
        const float x = sqrtf(dist2);
        const float e = KE * expf(-x);
        const float dotv = Q[mi] - cjv;
        const float w1v = e * dotv;
        const float w2v = e * (1.0f + x);
        w12[(m0 + mi) * NTRAIN + t] = make_float2(w1v, w2v);
        esv[mi] = w2v * dotv;
        s1v[mi] = w1v;
    }
    #pragma unroll
    for (int off = 32; off > 0; off >>= 1) {
        #pragma unroll
        for (int mi = 0; mi < 8; ++mi) {
            esv[mi] += __shfl_down(esv[mi], off, 64);
            s1v[mi] += __shfl_down(s1v[mi], off, 64);
        }
    }
    if ((tid & 63) == 0) {
        #pragma unroll
        for (int mi = 0; mi < 8; ++mi) {
            atomicAdd(&EsAcc[m0 + mi], esv[mi]);
            atomicAdd(&S1[m0 + mi], s1v[mi]);
        }
    }
}

// pass 2: F1[m,d] += sum_t w1[m,t]*b[t,d]; F2[m,d] += sum_t w2[m,t]*j[t,d].
// Block: 256 threads (d = tid), 8 m, t-chunk 128. Grid 32 x 16 = 512 (atomics
// back to R5's proven-cheap level). w-tile staged once; xj double-buffered, all gll16.
__global__ __launch_bounds__(256, 2) void k_pass2(const float2* __restrict__ xj2,
                                                  const float2* __restrict__ w12,
                                                  float* __restrict__ F1acc,
                                                  float* __restrict__ F2acc) {
    const int tid = threadIdx.x;
    const int t0 = blockIdx.x * 128;
    const int m0 = blockIdx.y * 8;

    __shared__ __align__(16) float2 wS[8][128];        // 8 KB  [mi][tt]
    __shared__ __align__(16) float2 xjS[2][8][256];    // 32 KB [buf][tt][d]

    // stage w-tile: 512 float4, 2 per thread
    #pragma unroll
    for (int k = 0; k < 2; ++k) {
        const int idx = tid + k * 256;
        const int mi = idx >> 6;          // wave-uniform per 64-lane group
        const int c16 = idx & 63;
        gll16(&w12[(m0 + mi) * NTRAIN + t0 + 2 * c16], &wS[mi][2 * c16]);
    }
    // stage xj chunk 0: 1024 float4, 4 per thread
    #pragma unroll
    for (int k = 0; k < 4; ++k) {
        const int idx = tid + k * 256;
        const int row = idx >> 7;
        const int col = idx & 127;
        gll16(&xj2[(t0 + row) * 256 + 2 * col], &xjS[0][row][2 * col]);
    }
    __syncthreads();

    const int d = (tid < DESC) ? tid : 0;
    float G1[8] = {0.f, 0.f, 0.f, 0.f, 0.f, 0.f, 0.f, 0.f};
    float G2[8] = {0.f, 0.f, 0.f, 0.f, 0.f, 0.f, 0.f, 0.f};

    for (int c = 0; c < 16; ++c) {
        const int cb = c & 1;
        if (c + 1 < 16) {
            #pragma unroll
            for (int k = 0; k < 4; ++k) {
                const int idx = tid + k * 256;
                const int row = idx >> 7;
                const int col = idx & 127;
                gll16(&xj2[(t0 + (c + 1) * 8 + row) * 256 + 2 * col],
                      &xjS[1 - cb][row][2 * col]);
            }
        }
        #pragma unroll
        for (int tp = 0; tp < 4; ++tp) {
            const int tb = c * 8 + tp * 2;
            float4 w0 = *reinterpret_cast<const float4*>(&wS[0][tb]);
            float4 w1 = *reinterpret_cast<const float4*>(&wS[1][tb]);
            float4 w2 = *reinterpret_cast<const float4*>(&wS[2][tb]);
            float4 w3 = *reinterpret_cast<const float4*>(&wS[3][tb]);
            float4 w4 = *reinterpret_cast<const float4*>(&wS[4][tb]);
            float4 w5 = *reinterpret_cast<const float4*>(&wS[5][tb]);
            float4 w6 = *reinterpret_cast<const float4*>(&wS[6][tb]);
            float4 w7 = *reinterpret_cast<const float4*>(&wS[7][tb]);
            const float2 xj0 = xjS[cb][tp * 2][d];
            const float2 xj1 = xjS[cb][tp * 2 + 1][d];
            G1[0] = fmaf(w0.x, xj0.x, G1[0]); G2[0] = fmaf(w0.y, xj0.y, G2[0]);
            G1[0] = fmaf(w0.z, xj1.x, G1[0]); G2[0] = fmaf(w0.w, xj1.y, G2[0]);
            G1[1] = fmaf(w1.x, xj0.x, G1[1]); G2[1] = fmaf(w1.y, xj0.y, G2[1]);
            G1[1] = fmaf(w1.z, xj1.x, G1[1]); G2[1] = fmaf(w1.w, xj1.y, G2[1]);
            G1[2] = fmaf(w2.x, xj0.x, G1[2]); G2[2] = fmaf(w2.y, xj0.y, G2[2]);
            G1[2] = fmaf(w2.z, xj1.x, G1[2]); G2[2] = fmaf(w2.w, xj1.y, G2[2]);
            G1[3] = fmaf(w3.x, xj0.x, G1[3]); G2[3] = fmaf(w3.y, xj0.y, G2[3]);
            G1[3] = fmaf(w3.z, xj1.x, G1[3]); G2[3] = fmaf(w3.w, xj1.y, G2[3]);
            G1[4] = fmaf(w4.x, xj0.x, G1[4]); G2[4] = fmaf(w4.y, xj0.y, G2[4]);
            G1[4] = fmaf(w4.z, xj1.x, G1[4]); G2[4] = fmaf(w4.w, xj1.y, G2[4]);
            G1[5] = fmaf(w5.x, xj0.x, G1[5]); G2[5] = fmaf(w5.y, xj0.y, G2[5]);
            G1[5] = fmaf(w5.z, xj1.x, G1[5]); G2[5] = fmaf(w5.w, xj1.y, G2[5]);
            G1[6] = fmaf(w6.x, xj0.x, G1[6]); G2[6] = fmaf(w6.y, xj0.y, G2[6]);
            G1[6] = fmaf(w6.z, xj1.x, G1[6]); G2[6] = fmaf(w6.w, xj1.y, G2[6]);
            G1[7] = fmaf(w7.x, xj0.x, G1[7]); G2[7] = fmaf(w7.y, xj0.y, G2[7]);
            G1[7] = fmaf(w7.z, xj1.x, G1[7]); G2[7] = fmaf(w7.w, xj1.y, G2[7]);
        }
        __syncthreads();
    }

    if (tid < DESC) {
        #pragma unroll
        for (int mi = 0; mi < 8; ++mi) {
            atomicAdd(&F1acc[(m0 + mi) * DESC + tid], G1[mi]);
            atomicAdd(&F2acc[(m0 + mi) * DESC + tid], G2[mi]);
        }
    }
}

// final assembly — coef, force scatter, Es
__global__ __launch_bounds__(256) void k_final(const float* __restrict__ Rs,
                                               const float* __restrict__ aT,
                                               const float* __restrict__ S1,
                                               const float* __restrict__ EsAcc,
                                               const float* __restrict__ F1acc,
                                               const float* __restrict__ F2acc,
                                               float* __restrict__ out) {
    const int m = blockIdx.x;
    __shared__ float R[NATOMS * 3];
    __shared__ float FsL[NATOMS * 3];
    const int tid = threadIdx.x;
    if (tid < NATOMS * 3) {
        R[tid] = Rs[m * NATOMS * 3 + tid];
        FsL[tid] = 0.0f;
    }
    __syncthreads();
    if (tid < DESC) {
        int i, j;
        pair_ij(tid, i, j);
        const float dx = R[i * 3 + 0] - R[j * 3 + 0];
        const float dy = R[i * 3 + 1] - R[j * 3 + 1];
        const float dz = R[i * 3 + 2] - R[j * 3 + 2];
        const float r2 = dx * dx + dy * dy + dz * dz;
        const float rinv = 1.0f / sqrtf(r2);
        const float a = aT[tid * NM + m];  // q/r
        const float F1 = a * S1[m] - F1acc[m * DESC + tid];
        const float Fx = (F1 - F2acc[m * DESC + tid]) * STDC;
        const float coef = Fx * (rinv * rinv * rinv);
        atomicAdd(&FsL[j * 3 + 0], coef * dx);
        atomicAdd(&FsL[j * 3 + 1], coef * dy);
        atomicAdd(&FsL[j * 3 + 2], coef * dz);
        atomicAdd(&FsL[i * 3 + 0], -coef * dx);
        atomicAdd(&FsL[i * 3 + 1], -coef * dy);
        atomicAdd(&FsL[i * 3 + 2], -coef * dz);
    }
    __syncthreads();
    if (tid < NATOMS * 3) out[NM + m * NATOMS * 3 + tid] = FsL[tid];
    if (tid == 0) out[m] = CC + (EsAcc[m] / QS) * STDC;
}

extern "C" void kernel_launch(void* const* d_in, const int* in_sizes, int n_in,
                              void* d_out, int out_size, void* d_ws, size_t ws_size,
                              hipStream_t stream) {
    const float* Rs = (const float*)d_in[0];
    const float* xs_train = (const float*)d_in[1];
    const float* Jx = (const float*)d_in[2];
    float* out = (float*)d_out;
    float* ws = (float*)d_ws;

    // zeroed prefix
    float* F1acc = ws;                         // 26880
    float* F2acc = ws + 26880;                 // 26880
    float* EsAcc = ws + 53760;                 // 128
    float* S1 = ws + 53888;                    // 128
    float* bsqA = ws + 54016;                  // 4096
    float* cjA = ws + 58112;                   // 4096  -> zero block ends at 62208
    // non-zeroed
    float* aT = ws + 62208;                    // 224*128 = 28672
    float* asq = ws + 90880;                   // 128
    float4* bjq = (float4*)(ws + 91008);       // 112*4096 float4 (16B aligned)
    float2* w12 = (float2*)(ws + 1926016);     // 128*4096 float2 (16B aligned)
    float2* xj2 = (float2*)(ws + 2974592);     // 4096*256 float2 (16B aligned)
    // end 5071744 floats (~20.3 MB)

    hipMemsetAsync(ws, 0, (size_t)62208 * sizeof(float), stream);

    k_prep<<<576, 256, 0, stream>>>(Rs, xs_train, Jx, bjq, xj2, aT, asq, bsqA, cjA);
    k_pass1<<<dim3(NTRAIN / 256, NM / 8), 256, 0, stream>>>(bjq, aT, asq, bsqA, cjA,
                                                            w12, EsAcc, S1);
    k_pass2<<<dim3(NTRAIN / 128, NM / 8), 256, 0, stream>>>(xj2, w12, F1acc, F2acc);
    k_final<<<NM, 256, 0, stream>>>(Rs, aT, S1, EsAcc, F1acc, F2acc, out);
}

// Round 8
// 80.453 us; speedup vs baseline: 1.7072x; 1.1667x over previous
//
#include <hip/hip_runtime.h>
#include <math.h>

#define NATOMS 21
#define DESC 210
#define DPAD 224          // padded descriptor count
#define P4 112            // DPAD/2 — float4-packed descriptor pairs
#define NTRAIN 4096
#define NM 128

#define CC 0.0f
#define STDC 1.0f
// q = sqrt(5)/sig
#define QS 0.22360679774997896f
// 5/(3*sig^2)
#define KE 0.016666666666666666f

// async global->LDS, 16B per lane, no VGPR round trip (guide §5 / T3)
__device__ __forceinline__ void gll16(const void* gptr, void* lptr) {
    __builtin_amdgcn_global_load_lds(
        (__attribute__((address_space(1))) void*)gptr,
        (__attribute__((address_space(3))) void*)lptr,
        16, 0, 0);
}

__device__ __forceinline__ void pair_ij(int p, int& i, int& j) {
    int ii = (int)((1.0f + sqrtf(1.0f + 8.0f * (float)p)) * 0.5f);
    while (ii * (ii - 1) / 2 > p) --ii;
    while ((ii + 1) * ii / 2 <= p) ++ii;
    i = ii;
    j = p - ii * (ii - 1) / 2;
}

// prep: blocks [0,448) transpose+pack xs/Jx into bjq (pass1) and xj2 (pass2),
//       accumulate bsq/cj per t; blocks [448,576) build aT, asq.
__global__ __launch_bounds__(256, 2) void k_prep(const float* __restrict__ Rs,
                                                 const float* __restrict__ xs_train,
                                                 const float* __restrict__ Jx,
                                                 float4* __restrict__ bjq,
                                                 float2* __restrict__ xj2,
                                                 float* __restrict__ aT,
                                                 float* __restrict__ asq,
                                                 float* __restrict__ bsqA,
                                                 float* __restrict__ cjA) {
    __shared__ float smem[2 * 32 * 65 + 8];
    const int tid = threadIdx.x;
    const int bid = blockIdx.x;
    if (bid < 448) {
        float* ldsX = smem;
        float* ldsJ = smem + 32 * 65;
        const int bx = bid & 63;        // t tile
        const int by = bid >> 6;        // d tile (0..6)
        const int t0 = bx * 64;
        const int d0 = by * 32;
        #pragma unroll
        for (int k = 0; k < 8; ++k) {
            const int idx = tid + k * 256;        // 64t x 32d
            const int tt = idx >> 5;
            const int dd = idx & 31;
            const int d = d0 + dd;
            float xv = 0.0f, jv = 0.0f;
            if (d < DESC) {
                xv = QS * xs_train[(t0 + tt) * DESC + d];
                jv = Jx[(t0 + tt) * DESC + d];
            }
            ldsX[dd * 65 + tt] = xv;
            ldsJ[dd * 65 + tt] = jv;
        }
        __syncthreads();
        #pragma unroll
        for (int k = 0; k < 4; ++k) {
            const int idx = tid + k * 256;        // 16p x 64t
            const int pp = idx >> 6;
            const int tt = idx & 63;
            float4 v;
            v.x = ldsX[(2 * pp) * 65 + tt];
            v.y = ldsJ[(2 * pp) * 65 + tt];
            v.z = ldsX[(2 * pp + 1) * 65 + tt];
            v.w = ldsJ[(2 * pp + 1) * 65 + tt];
            bjq[(by * 16 + pp) * NTRAIN + t0 + tt] = v;
        }
        // pass2 layout: xj2[t][256] = {q*xs, Jx}
        #pragma unroll
        for (int k = 0; k < 8; ++k) {
            const int idx = tid + k * 256;        // 64t x 32d
            const int tt = idx >> 5;
            const int dd = idx & 31;
            xj2[(t0 + tt) * 256 + d0 + dd] =
                make_float2(ldsX[dd * 65 + tt], ldsJ[dd * 65 + tt]);
        }
        // per-t partials of sum_d b^2 and sum_d b*j over this 32-d tile
        if (tid < 64) {
            float sb = 0.0f, sc = 0.0f;
            #pragma unroll
            for (int dd = 0; dd < 32; ++dd) {
                const float b = ldsX[dd * 65 + tid];
                const float jj = ldsJ[dd * 65 + tid];
                sb = fmaf(b, b, sb);
                sc = fmaf(b, jj, sc);
            }
            atomicAdd(&bsqA[t0 + tid], sb);
            atomicAdd(&cjA[t0 + tid], sc);
        }
    } else {
        const int m = bid - 448;
        float* R = smem;
        float* red = smem + 64;
        if (tid < NATOMS * 3) R[tid] = Rs[m * NATOMS * 3 + tid];
        __syncthreads();
        float a2 = 0.0f;
        if (tid < DPAD) {
            float a = 0.0f;
            if (tid < DESC) {
                int i, j;
                pair_ij(tid, i, j);
                const float dx = R[i * 3 + 0] - R[j * 3 + 0];
                const float dy = R[i * 3 + 1] - R[j * 3 + 1];
                const float dz = R[i * 3 + 2] - R[j * 3 + 2];
                a = QS / sqrtf(dx * dx + dy * dy + dz * dz);
            }
            aT[tid * NM + m] = a;
            a2 = a * a;
        }
        #pragma unroll
        for (int off = 32; off > 0; off >>= 1) a2 += __shfl_down(a2, off, 64);
        if ((tid & 63) == 0) red[tid >> 6] = a2;
        __syncthreads();
        if (tid == 0) asq[m] = red[0] + red[1] + red[2] + red[3];
    }
}

// pass 1: 64 t x 16 m per block; thread = (t, m-quad), wave = m-quad (aS reads
// wave-uniform). gll16 double-buffered 16-row chunks. Grid 512 linear, decoded
// so all 8 m-groups of a t-tile share bid%8 (same XCD under round-robin) ->
// each XCD's bjq working set = 8 t-tiles x 112 KB = 896 KB = L2-resident.
__global__ __launch_bounds__(256, 2) void k_pass1(const float4* __restrict__ bjq,
                                                  const float* __restrict__ aT,
                                                  const float* __restrict__ asq,
                                                  const float* __restrict__ bsqA,
                                                  const float* __restrict__ cjA,
                                                  float2* __restrict__ w12,
                                                  float* __restrict__ EsAcc,
                                                  float* __restrict__ S1) {
    const int tid = threadIdx.x;
    const int bid = blockIdx.x;
    const int bx = (bid & 7) + 8 * (bid >> 6);   // t-tile 0..63
    const int my = (bid >> 3) & 7;               // m-group 0..7
    const int t0 = bx * 64;
    const int m0 = my * 16;
    const int t = tid & 63;
    const int mq = tid >> 6;                     // 0..3, wave-uniform

    __shared__ __align__(16) float aS[P4][32];          // 14 KB: [p]{d0:m0..15, d1:m0..15}
    __shared__ __align__(16) float4 bjS[2][16][64];     // 2 x 16 KB

    #pragma unroll
    for (int k = 0; k < 14; ++k) {
        const int idx = tid + k * 256;   // 112*32 = 3584
        const int p = idx >> 5;
        const int c = idx & 31;
        aS[p][c] = aT[(2 * p + (c >> 4)) * NM + m0 + (c & 15)];
    }
    // stage chunk 0 (16 rows x 64 t = 1024 float4; 4 per thread)
    #pragma unroll
    for (int k = 0; k < 4; ++k) {
        const int idx = tid + k * 256;
        const int row = idx >> 6;        // wave-uniform
        const int col = idx & 63;
        gll16(&bjq[row * NTRAIN + t0 + col], &bjS[0][row][col]);
    }
    __syncthreads();

    float P[4] = {0.f, 0.f, 0.f, 0.f};
    float Q[4] = {0.f, 0.f, 0.f, 0.f};

    for (int c = 0; c < 7; ++c) {
        const int cb = c & 1;
        if (c + 1 < 7) {
            #pragma unroll
            for (int k = 0; k < 4; ++k) {
                const int idx = tid + k * 256;
                const int row = idx >> 6;
                const int col = idx & 63;
                gll16(&bjq[((c + 1) * 16 + row) * NTRAIN + t0 + col],
                      &bjS[1 - cb][row][col]);
            }
        }
        #pragma unroll
        for (int u = 0; u < 16; ++u) {
            const int p = c * 16 + u;
            const float4 bj = bjS[cb][u][t];
            const float4 aA = *reinterpret_cast<const float4*>(&aS[p][mq * 4]);
            const float4 aB = *reinterpret_cast<const float4*>(&aS[p][16 + mq * 4]);
            P[0] = fmaf(aA.x, bj.x, P[0]); P[1] = fmaf(aA.y, bj.x, P[1]);
            P[2] = fmaf(aA.z, bj.x, P[2]); P[3] = fmaf(aA.w, bj.x, P[3]);
            Q[0] = fmaf(aA.x, bj.y, Q[0]); Q[1] = fmaf(aA.y, bj.y, Q[1]);
            Q[2] = fmaf(aA.z, bj.y, Q[2]); Q[3] = fmaf(aA.w, bj.y, Q[3]);
            P[0] = fmaf(aB.x, bj.z, P[0]); P[1] = fmaf(aB.y, bj.z, P[1]);
            P[2] = fmaf(aB.z, bj.z, P[2]); P[3] = fmaf(aB.w, bj.z, P[3]);
            Q[0] = fmaf(aB.x, bj.w, Q[0]); Q[1] = fmaf(aB.y, bj.w, Q[1]);
            Q[2] = fmaf(aB.z, bj.w, Q[2]); Q[3] = fmaf(aB.w, bj.w, Q[3]);
        }
        __syncthreads();
    }

    const float bsqv = bsqA[t0 + t];
    const float cjv = cjA[t0 + t];
    float esv[4], s1v[4];
    #pragma unroll
    for (int i = 0; i < 4; ++i) {
        const int m = m0 + mq * 4 + i;
        float dist2 = asq[m] + bsqv - 2.0f * P[i];
        dist2 = fmaxf(dist2, 0.0f);
        const float x = sqrtf(dist2);
        const float e = KE * expf(-x);
        const float dotv = Q[i] - cjv;
        const float w1v = e * dotv;
        const float w2v = e * (1.0f + x);
        w12[m * NTRAIN + t0 + t] = make_float2(w1v, w2v);
        esv[i] = w2v * dotv;
        s1v[i] = w1v;
    }
    #pragma unroll
    for (int off = 32; off > 0; off >>= 1) {
        #pragma unroll
        for (int i = 0; i < 4; ++i) {
            esv[i] += __shfl_down(esv[i], off, 64);
            s1v[i] += __shfl_down(s1v[i], off, 64);
        }
    }
    if ((tid & 63) == 0) {
        #pragma unroll
        for (int i = 0; i < 4; ++i) {
            atomicAdd(&EsAcc[m0 + mq * 4 + i], esv[i]);
            atomicAdd(&S1[m0 + mq * 4 + i], s1v[i]);
        }
    }
}

// pass 2: F1[m,d] += sum_t w1[m,t]*b[t,d]; F2[m,d] += sum_t w2[m,t]*j[t,d].
// 256 threads (d = tid), 8 m, t-chunk 128. Grid 512 linear with the same
// t-locality XCD decode. w-tile staged once; xj double-buffered, all gll16.
__global__ __launch_bounds__(256, 2) void k_pass2(const float2* __restrict__ xj2,
                                                  const float2* __restrict__ w12,
                                                  float* __restrict__ F1acc,
                                                  float* __restrict__ F2acc) {
    const int tid = threadIdx.x;
    const int bid = blockIdx.x;
    const int bx = (bid & 7) + 8 * (bid >> 7);   // t-tile 0..31
    const int my = (bid >> 3) & 15;              // m-group 0..15
    const int t0 = bx * 128;
    const int m0 = my * 8;

    __shared__ __align__(16) float2 wS[8][128];        // 8 KB  [mi][tt]
    __shared__ __align__(16) float2 xjS[2][8][256];    // 32 KB [buf][tt][d]

    // stage w-tile: 512 float4, 2 per thread
    #pragma unroll
    for (int k = 0; k < 2; ++k) {
        const int idx = tid + k * 256;
        const int mi = idx >> 6;          // wave-uniform per 64-lane group
        const int c16 = idx & 63;
        gll16(&w12[(m0 + mi) * NTRAIN + t0 + 2 * c16], &wS[mi][2 * c16]);
    }
    // stage xj chunk 0: 1024 float4, 4 per thread
    #pragma unroll
    for (int k = 0; k < 4; ++k) {
        const int idx = tid + k * 256;
        const int row = idx >> 7;
        const int col = idx & 127;
        gll16(&xj2[(t0 + row) * 256 + 2 * col], &xjS[0][row][2 * col]);
    }
    __syncthreads();

    const int d = (tid < DESC) ? tid : 0;
    float G1[8] = {0.f, 0.f, 0.f, 0.f, 0.f, 0.f, 0.f, 0.f};
    float G2[8] = {0.f, 0.f, 0.f, 0.f, 0.f, 0.f, 0.f, 0.f};

    for (int c = 0; c < 16; ++c) {
        const int cb = c & 1;
        if (c + 1 < 16) {
            #pragma unroll
            for (int k = 0; k < 4; ++k) {
                const int idx = tid + k * 256;
                const int row = idx >> 7;
                const int col = idx & 127;
                gll16(&xj2[(t0 + (c + 1) * 8 + row) * 256 + 2 * col],
                      &xjS[1 - cb][row][2 * col]);
            }
        }
        #pragma unroll
        for (int tp = 0; tp < 4; ++tp) {
            const int tb = c * 8 + tp * 2;
            float4 w0 = *reinterpret_cast<const float4*>(&wS[0][tb]);
            float4 w1 = *reinterpret_cast<const float4*>(&wS[1][tb]);
            float4 w2 = *reinterpret_cast<const float4*>(&wS[2][tb]);
            float4 w3 = *reinterpret_cast<const float4*>(&wS[3][tb]);
            float4 w4 = *reinterpret_cast<const float4*>(&wS[4][tb]);
            float4 w5 = *reinterpret_cast<const float4*>(&wS[5][tb]);
            float4 w6 = *reinterpret_cast<const float4*>(&wS[6][tb]);
            float4 w7 = *reinterpret_cast<const float4*>(&wS[7][tb]);
            const float2 xj0 = xjS[cb][tp * 2][d];
            const float2 xj1 = xjS[cb][tp * 2 + 1][d];
            G1[0] = fmaf(w0.x, xj0.x, G1[0]); G2[0] = fmaf(w0.y, xj0.y, G2[0]);
            G1[0] = fmaf(w0.z, xj1.x, G1[0]); G2[0] = fmaf(w0.w, xj1.y, G2[0]);
            G1[1] = fmaf(w1.x, xj0.x, G1[1]); G2[1] = fmaf(w1.y, xj0.y, G2[1]);
            G1[1] = fmaf(w1.z, xj1.x, G1[1]); G2[1] = fmaf(w1.w, xj1.y, G2[1]);
            G1[2] = fmaf(w2.x, xj0.x, G1[2]); G2[2] = fmaf(w2.y, xj0.y, G2[2]);
            G1[2] = fmaf(w2.z, xj1.x, G1[2]); G2[2] = fmaf(w2.w, xj1.y, G2[2]);
            G1[3] = fmaf(w3.x, xj0.x, G1[3]); G2[3] = fmaf(w3.y, xj0.y, G2[3]);
            G1[3] = fmaf(w3.z, xj1.x, G1[3]); G2[3] = fmaf(w3.w, xj1.y, G2[3]);
            G1[4] = fmaf(w4.x, xj0.x, G1[4]); G2[4] = fmaf(w4.y, xj0.y, G2[4]);
            G1[4] = fmaf(w4.z, xj1.x, G1[4]); G2[4] = fmaf(w4.w, xj1.y, G2[4]);
            G1[5] = fmaf(w5.x, xj0.x, G1[5]); G2[5] = fmaf(w5.y, xj0.y, G2[5]);
            G1[5] = fmaf(w5.z, xj1.x, G1[5]); G2[5] = fmaf(w5.w, xj1.y, G2[5]);
            G1[6] = fmaf(w6.x, xj0.x, G1[6]); G2[6] = fmaf(w6.y, xj0.y, G2[6]);
            G1[6] = fmaf(w6.z, xj1.x, G1[6]); G2[6] = fmaf(w6.w, xj1.y, G2[6]);
            G1[7] = fmaf(w7.x, xj0.x, G1[7]); G2[7] = fmaf(w7.y, xj0.y, G2[7]);
            G1[7] = fmaf(w7.z, xj1.x, G1[7]); G2[7] = fmaf(w7.w, xj1.y, G2[7]);
        }
        __syncthreads();
    }

    if (tid < DESC) {
        #pragma unroll
        for (int mi = 0; mi < 8; ++mi) {
            atomicAdd(&F1acc[(m0 + mi) * DESC + tid], G1[mi]);
            atomicAdd(&F2acc[(m0 + mi) * DESC + tid], G2[mi]);
        }
    }
}

// final assembly — coef, force scatter, Es
__global__ __launch_bounds__(256) void k_final(const float* __restrict__ Rs,
                                               const float* __restrict__ aT,
                                               const float* __restrict__ S1,
                                               const float* __restrict__ EsAcc,
                                               const float* __restrict__ F1acc,
                                               const float* __restrict__ F2acc,
                                               float* __restrict__ out) {
    const int m = blockIdx.x;
    __shared__ float R[NATOMS * 3];
    __shared__ float FsL[NATOMS * 3];
    const int tid = threadIdx.x;
    if (tid < NATOMS * 3) {
        R[tid] = Rs[m * NATOMS * 3 + tid];
        FsL[tid] = 0.0f;
    }
    __syncthreads();
    if (tid < DESC) {
        int i, j;
        pair_ij(tid, i, j);
        const float dx = R[i * 3 + 0] - R[j * 3 + 0];
        const float dy = R[i * 3 + 1] - R[j * 3 + 1];
        const float dz = R[i * 3 + 2] - R[j * 3 + 2];
        const float r2 = dx * dx + dy * dy + dz * dz;
        const float rinv = 1.0f / sqrtf(r2);
        const float a = aT[tid * NM + m];  // q/r
        const float F1 = a * S1[m] - F1acc[m * DESC + tid];
        const float Fx = (F1 - F2acc[m * DESC + tid]) * STDC;
        const float coef = Fx * (rinv * rinv * rinv);
        atomicAdd(&FsL[j * 3 + 0], coef * dx);
        atomicAdd(&FsL[j * 3 + 1], coef * dy);
        atomicAdd(&FsL[j * 3 + 2], coef * dz);
        atomicAdd(&FsL[i * 3 + 0], -coef * dx);
        atomicAdd(&FsL[i * 3 + 1], -coef * dy);
        atomicAdd(&FsL[i * 3 + 2], -coef * dz);
    }
    __syncthreads();
    if (tid < NATOMS * 3) out[NM + m * NATOMS * 3 + tid] = FsL[tid];
    if (tid == 0) out[m] = CC + (EsAcc[m] / QS) * STDC;
}

extern "C" void kernel_launch(void* const* d_in, const int* in_sizes, int n_in,
                              void* d_out, int out_size, void* d_ws, size_t ws_size,
                              hipStream_t stream) {
    const float* Rs = (const float*)d_in[0];
    const float* xs_train = (const float*)d_in[1];
    const float* Jx = (const float*)d_in[2];
    float* out = (float*)d_out;
    float* ws = (float*)d_ws;

    // zeroed prefix
    float* F1acc = ws;                         // 26880
    float* F2acc = ws + 26880;                 // 26880
    float* EsAcc = ws + 53760;                 // 128
    float* S1 = ws + 53888;                    // 128
    float* bsqA = ws + 54016;                  // 4096
    float* cjA = ws + 58112;                   // 4096  -> zero block ends at 62208
    // non-zeroed
    float* aT = ws + 62208;                    // 224*128 = 28672
    float* asq = ws + 90880;                   // 128
    float4* bjq = (float4*)(ws + 91008);       // 112*4096 float4 (16B aligned)
    float2* w12 = (float2*)(ws + 1926016);     // 128*4096 float2 (16B aligned)
    float2* xj2 = (float2*)(ws + 2974592);     // 4096*256 float2 (16B aligned)
    // end 5071744 floats (~20.3 MB)

    hipMemsetAsync(ws, 0, (size_t)62208 * sizeof(float), stream);

    k_prep<<<576, 256, 0, stream>>>(Rs, xs_train, Jx, bjq, xj2, aT, asq, bsqA, cjA);
    k_pass1<<<512, 256, 0, stream>>>(bjq, aT, asq, bsqA, cjA, w12, EsAcc, S1);
    k_pass2<<<512, 256, 0, stream>>>(xj2, w12, F1acc, F2acc);
    k_final<<<NM, 256, 0, stream>>>(Rs, aT, S1, EsAcc, F1acc, F2acc, out);
}